// Round 6
// baseline (307.604 us; speedup 1.0000x reference)
//
#include <hip/hip_runtime.h>

// FM_FTRL == two unit-lower-triangular solves (R1/R2 analysis):
//   alpha_i = -2eta*(x_0.x_i - q0*q_i)  (closed form, K_A=1; alpha_0 = 1)
//   (I+Lh)s = r, Lh[i,j] = 2eta*(x_j.x_i) j<i
//   r_i = 2*(alpha_i^2*T0 - b_i) (i>=1), r_0 = 2*(s0 + T0 - b_0)
//   preds = s/2 + b ;  K_B=2: s ~= r - L r + L^2 r
// L*v via chunking (C=100): per-chunk sums Z -> scan kernel -> prefix S,
// plus packed chunk-local Grams. 6 launches, no cooperative sync.
// R6: k_gram 8x8 reg tiles + launch_bounds(1024,4) (R4's 8x8 spilled at the
// default 64-VGPR cap); k_term sweep1 vectorized float4-over-i.

#define NN 20000
#define CC 100
#define PCH 200
#define ETA2 2e-5f

// ws float offsets (total ~7.4 MB)
#define OFF_GRAM 0L          // 200 chunks x 4960 packed lower-tri
#define OFF_ZR   992000L
#define OFF_Z1   1196800L
#define OFF_S1   1401600L
#define OFF_S2   1606400L
#define OFF_SCLP 1811200L    // [0..31] T0 partials, [32] s0
#define OFF_ACC  1811240L
#define OFF_TV   1831240L

// ---------------- k0: T0/s0 partials + b-copy ------------------------------
__global__ __launch_bounds__(1024) void k_init(
    const float* __restrict__ At, const float* __restrict__ bvec,
    const float* __restrict__ w1, const float* __restrict__ W2,
    float* __restrict__ out, float* __restrict__ scalp) {
  __shared__ float x0s[1024];
  __shared__ float part[16];
  const int bid = blockIdx.x, t = threadIdx.x;
  const int wid = t >> 6, lane = t & 63;

  if (bid < 32) {  // T0 partial over 16 W2 rows
    x0s[t] = (t < 1023) ? At[(long)t * NN] : 0.f;
    __syncthreads();
    const int row = bid * 16 + wid;
    float p = 0.f;
#pragma unroll
    for (int k = 0; k < 16; ++k) {
      const int ci = k * 64 + lane;
      if (ci < 1023) p = fmaf(W2[(long)row * 1023 + ci], x0s[ci], p);
    }
#pragma unroll
    for (int o = 32; o > 0; o >>= 1) p += __shfl_down(p, o);
    if (lane == 0) part[wid] = p * p;
    __syncthreads();
    if (t == 0) {
      float s = 0.f;
#pragma unroll
      for (int k = 0; k < 16; ++k) s += part[k];
      scalp[bid] = s;
    }
  } else if (bid == 32) {  // s0 = w1 . x0
    float p = w1[t] * At[(long)t * NN];
#pragma unroll
    for (int o = 32; o > 0; o >>= 1) p += __shfl_down(p, o);
    if (lane == 0) part[wid] = p;
    __syncthreads();
    if (t == 0) {
      float s = 0.f;
#pragma unroll
      for (int k = 0; k < 16; ++k) s += part[k];
      scalp[32] = s;
    }
  } else {  // b-copy: 20 blocks x 1000
    const int i = (bid - 33) * 1000 + t;
    if (t < 1000) out[NN + i] = bvec[i];
  }
}

// ---------------- k1: packed chunk Grams + alpha + r + Zr ------------------
struct GramSh {
  float xt[128 * 104];            // 53,248 B stage tile [e=128][i=104]
  float scr[91 * 66];             // 24,024 B band-reduce slot (pad 66)
  float x0s[1024];
  float up[CC];
  __align__(16) float rs[CC];
  float sc[2];
};

__global__ __launch_bounds__(1024, 4) void k_gram(
    const float* __restrict__ At, const float* __restrict__ bvec,
    float* __restrict__ gram, float* __restrict__ Zr,
    const float* __restrict__ scalp, float* __restrict__ acc) {
  __shared__ GramSh sh;
  const int c = blockIdx.x, t = threadIdx.x;
  const long i0 = (long)c * CC;

  sh.x0s[t] = At[(long)t * NN];
  if (t == 0) {
    float T = 0.f;
#pragma unroll
    for (int k = 0; k < 32; ++k) T += scalp[k];
    sh.sc[0] = T;
    sh.sc[1] = scalp[32];
  }

  // gram threads: 4 e-bands x 91 lower-tri 8x8 tiles (13x13 grid)
  const bool gact = (t < 364);
  int a = 0, bb = 0, band = 0, tile = 0;
  if (gact) {
    tile = t % 91; band = t / 91;
    int r = tile; while (r > a) { r -= ++a; } bb = r;
  }
  // u threads: 100 threads (364..463): u_i = sum_e X[e][i0+i]*x0[e]
  const bool uact = (t >= 364 && t < 464);
  const int ui = t - 364;
  float uacc = 0.f;

  float ac[8][8];
#pragma unroll
  for (int r = 0; r < 8; ++r)
#pragma unroll
    for (int s = 0; s < 8; ++s) ac[r][s] = 0.f;

  for (int st = 0; st < 8; ++st) {
    __syncthreads();
#pragma unroll
    for (int k = 0; k < 4; ++k) {  // 3328 float4 groups (rows of 26)
      const int idx = t + k * 1024;
      if (idx < 3328) {
        const int e = idx / 26, j = idx - 26 * e;
        if (j < 25) {
          const float4 f =
              *(const float4*)(At + (long)(st * 128 + e) * NN + i0 + 4 * j);
          *(float4*)&sh.xt[e * 104 + 4 * j] = f;
        } else {
          *(float4*)&sh.xt[e * 104 + 100] = make_float4(0.f, 0.f, 0.f, 0.f);
        }
      }
    }
    __syncthreads();
    if (gact) {
      const int e0 = band * 32;
#pragma unroll 2
      for (int le = e0; le < e0 + 32; ++le) {
        const float* row = &sh.xt[le * 104];
        float ra[8], rb[8];
        *(float4*)&ra[0] = *(const float4*)(row + 8 * a);
        *(float4*)&ra[4] = *(const float4*)(row + 8 * a + 4);
        *(float4*)&rb[0] = *(const float4*)(row + 8 * bb);
        *(float4*)&rb[4] = *(const float4*)(row + 8 * bb + 4);
#pragma unroll
        for (int r = 0; r < 8; ++r)
#pragma unroll
          for (int s = 0; s < 8; ++s) ac[r][s] = fmaf(ra[r], rb[s], ac[r][s]);
      }
    } else if (uact) {
#pragma unroll 4
      for (int le = 0; le < 128; ++le)
        uacc = fmaf(sh.xt[le * 104 + ui], sh.x0s[st * 128 + le], uacc);
    }
  }
  if (uact) sh.up[ui] = uacc;
  __syncthreads();

  // alpha (closed form) -> r ;  q_i = X[1023][i] = xt row 127 (still intact)
  if (t < CC) {
    const long gi = i0 + t;
    const float uu = sh.up[t];
    const float qi = sh.xt[127 * 104 + t];
    const float q0 = sh.x0s[1023];
    const float al = (gi == 0) ? 1.f : -ETA2 * (uu - q0 * qi);
    const float T0 = sh.sc[0], s0v = sh.sc[1];
    const float bv = bvec[gi];
    float r = 2.f * fmaf(al * al, T0, -bv);
    if (gi == 0) r = 2.f * (s0v + T0 - bv);
    sh.rs[t] = r;
    acc[gi] = r;
  }
  __syncthreads();

  // Zr[c][e] = sum_j r_j X[e][i0+j]  (chunk rows are L2-hot)
  {
    const float* xr = At + (long)t * NN + i0;
    float z = 0.f;
#pragma unroll
    for (int j4 = 0; j4 < 25; ++j4) {
      const float4 x = *(const float4*)(xr + 4 * j4);
      const float4 rq = *(const float4*)&sh.rs[4 * j4];
      z = fmaf(x.x, rq.x, z); z = fmaf(x.y, rq.y, z);
      z = fmaf(x.z, rq.z, z); z = fmaf(x.w, rq.w, z);
    }
    Zr[(long)c * 1024 + t] = z;
  }

  // sequential band reduce: bands 1..3 into band 0 (padded slot, 2-way max)
#pragma unroll
  for (int rb = 1; rb <= 3; ++rb) {
    __syncthreads();
    if (gact && band == rb) {
      float* dst = &sh.scr[tile * 66];
#pragma unroll
      for (int r = 0; r < 8; ++r) {
        *(float4*)&dst[r * 8] = make_float4(ac[r][0], ac[r][1], ac[r][2], ac[r][3]);
        *(float4*)&dst[r * 8 + 4] = make_float4(ac[r][4], ac[r][5], ac[r][6], ac[r][7]);
      }
    }
    __syncthreads();
    if (gact && band == 0) {
      const float* src = &sh.scr[tile * 66];
#pragma unroll
      for (int r = 0; r < 8; ++r)
#pragma unroll
        for (int s = 0; s < 8; ++s) ac[r][s] += src[r * 8 + s];
    }
  }
  if (gact && band == 0) {
    float* gp = gram + (long)c * 4960;
#pragma unroll
    for (int r = 0; r < 8; ++r) {
      const int row = 8 * a + r;
      if (row < CC) {
        const int base = row * (row - 1) / 2;
#pragma unroll
        for (int s = 0; s < 8; ++s) {
          const int col = 8 * bb + s;
          if (col < row) gp[base + col] = ac[r][s];
        }
      }
    }
  }
}

// ---------------- scan: S[c][e] = sum_{cp<c} Z[cp][e] ----------------------
__global__ __launch_bounds__(64) void k_scan(const float* __restrict__ Z,
                                             float* __restrict__ S) {
  const int e = blockIdx.x * 64 + threadIdx.x;
  float s = 0.f;
#pragma unroll 4
  for (int c = 0; c < PCH; ++c) {
    S[(long)c * 1024 + e] = s;
    s += Z[(long)c * 1024 + e];
  }
}

// ---------------- term: w = -(L v)  ----------------------------------------
// LAST=false: v = r (acc), w = t1 ; tvec=t1, acc=r+t1, Z1.
// LAST=true : v = t1 (tvec), w = t2 ; out = 0.5*(acc+t2) + b.
template <bool LAST>
__global__ __launch_bounds__(1024) void k_term(
    const float* __restrict__ At, const float* __restrict__ bvec,
    const float* __restrict__ gram, const float* __restrict__ S,
    float* __restrict__ Z1, float* __restrict__ acc, float* __restrict__ tvec,
    float* __restrict__ out) {
  __shared__ float Sm[1024];
  __shared__ float red[32 * 104];   // [band][100 + pad]
  __shared__ __align__(16) float vvs[CC], wvs[CC];
  const int c = blockIdx.x, t = threadIdx.x;
  const long i0 = (long)c * CC;

  Sm[t] = S[(long)c * 1024 + t];
  if (t < CC) vvs[t] = LAST ? tvec[i0 + t] : acc[i0 + t];
  __syncthreads();

  // sweep1: dot_i = x_i . S  -- 800 threads: i4 = t&31 (<25), tb = t>>5
  {
    const int i4 = t & 31, tb = t >> 5;
    if (i4 < 25) {
      const float* base = At + i0 + 4 * i4;
      float d0 = 0.f, d1 = 0.f, d2 = 0.f, d3 = 0.f;
#pragma unroll 8
      for (int e = tb * 32; e < tb * 32 + 32; ++e) {
        const float4 x = *(const float4*)(base + (long)e * NN);
        const float sm = Sm[e];
        d0 = fmaf(x.x, sm, d0); d1 = fmaf(x.y, sm, d1);
        d2 = fmaf(x.z, sm, d2); d3 = fmaf(x.w, sm, d3);
      }
      *(float4*)&red[tb * 104 + 4 * i4] = make_float4(d0, d1, d2, d3);
    }
  }
  __syncthreads();

  if (t < CC) {
    const int i = t;
    float dot = 0.f;
#pragma unroll
    for (int tb = 0; tb < 32; ++tb) dot += red[tb * 104 + i];
    const float* grow = gram + (long)c * 4960 + i * (i - 1) / 2;
    float g = 0.f;
#pragma unroll 4
    for (int j = 0; j < i; ++j) g = fmaf(grow[j], vvs[j], g);
    const float w = -ETA2 * (dot + g);
    if (LAST) {
      out[i0 + i] = fmaf(0.5f, acc[i0 + i] + w, bvec[i0 + i]);
    } else {
      wvs[i] = w;
      tvec[i0 + i] = w;
      acc[i0 + i] += w;
    }
  }
  if (!LAST) {
    __syncthreads();
    const float* xr = At + (long)t * NN + i0;
    float z = 0.f;
#pragma unroll
    for (int j4 = 0; j4 < 25; ++j4) {
      const float4 x = *(const float4*)(xr + 4 * j4);
      const float4 wq = *(const float4*)&wvs[4 * j4];
      z = fmaf(x.x, wq.x, z); z = fmaf(x.y, wq.y, z);
      z = fmaf(x.z, wq.z, z); z = fmaf(x.w, wq.w, z);
    }
    Z1[(long)c * 1024 + t] = z;
  }
}

extern "C" void kernel_launch(void* const* d_in, const int* in_sizes, int n_in,
                              void* d_out, int out_size, void* d_ws,
                              size_t ws_size, hipStream_t stream) {
  const float* At = (const float*)d_in[0];  // (1024, 20000) row-major
  const float* b  = (const float*)d_in[1];
  const float* w1 = (const float*)d_in[2];
  const float* W2 = (const float*)d_in[3];  // (512, 1023) row-major
  float* out = (float*)d_out;
  float* ws = (float*)d_ws;

  float* gram  = ws + OFF_GRAM;
  float* Zr    = ws + OFF_ZR;
  float* Z1    = ws + OFF_Z1;
  float* S1    = ws + OFF_S1;
  float* S2    = ws + OFF_S2;
  float* scalp = ws + OFF_SCLP;
  float* acc   = ws + OFF_ACC;
  float* tvec  = ws + OFF_TV;

  k_init<<<dim3(53), dim3(1024), 0, stream>>>(At, b, w1, W2, out, scalp);
  k_gram<<<dim3(PCH), dim3(1024), 0, stream>>>(At, b, gram, Zr, scalp, acc);
  k_scan<<<dim3(16), dim3(64), 0, stream>>>(Zr, S1);
  k_term<false><<<dim3(PCH), dim3(1024), 0, stream>>>(At, b, gram, S1, Z1, acc,
                                                      tvec, out);
  k_scan<<<dim3(16), dim3(64), 0, stream>>>(Z1, S2);
  k_term<true><<<dim3(PCH), dim3(1024), 0, stream>>>(At, b, gram, S2, Z1, acc,
                                                     tvec, out);
}